// Round 1
// baseline (1015.317 us; speedup 1.0000x reference)
//
#include <hip/hip_runtime.h>
#include <cstdint>
#include <cstddef>

#define B_   16
#define C_   512
#define H_   32
#define W_   32
#define HW_  1024
#define TC_  64
#define T_   48

// ---------------------------------------------------------------------------
// 1) column sums of squares: x viewed as [B*C=8192, HW=1024]; deterministic
//    2-stage reduce. partial[32][1024]
// ---------------------------------------------------------------------------
__global__ void k_colsq(const float* __restrict__ x, float* __restrict__ partial) {
    int bid = blockIdx.x;            // 128 blocks: 4 col-tiles x 32 row-tiles
    int col = (bid & 3) * 256 + threadIdx.x;
    int r0  = (bid >> 2) * 256;
    const float* p = x + (size_t)r0 * HW_ + col;
    float s = 0.f;
    for (int r = 0; r < 256; ++r) {
        float v = p[(size_t)r * HW_];
        s += v * v;
    }
    partial[(size_t)(bid >> 2) * HW_ + col] = s;
}

__global__ void k_rsqrt(const float* __restrict__ partial, float* __restrict__ ninv) {
    int i = blockIdx.x * 256 + threadIdx.x;
    if (i < HW_) {
        float s = 0.f;
        for (int r = 0; r < 32; ++r) s += partial[(size_t)r * HW_ + i];
        ninv[i] = rsqrtf(s);
    }
}

// ---------------------------------------------------------------------------
// 2) transpose + normalize: x [B, C, HW] -> xnT [B, HW, C], scaled by ninv[m]
// ---------------------------------------------------------------------------
__global__ void k_transpose(const float* __restrict__ x, const float* __restrict__ ninv,
                            float* __restrict__ xnT) {
    __shared__ float tile[32][33];
    int b  = blockIdx.z;
    int m0 = blockIdx.x * 32;   // HW coord
    int c0 = blockIdx.y * 32;   // C coord
    int tx = threadIdx.x, ty = threadIdx.y;   // 32 x 8
    const float* xb = x + (size_t)b * C_ * HW_;
    #pragma unroll
    for (int j = 0; j < 32; j += 8)
        tile[ty + j][tx] = xb[(size_t)(c0 + ty + j) * HW_ + m0 + tx];
    __syncthreads();
    float* ob = xnT + (size_t)b * HW_ * C_;
    #pragma unroll
    for (int j = 0; j < 32; j += 8) {
        int m = m0 + ty + j;
        ob[(size_t)m * C_ + c0 + tx] = tile[tx][ty + j] * ninv[m];
    }
}

// ---------------------------------------------------------------------------
// 3) generic fp32 tiled GEMM, 64x64 tile, K-step 16, 256 threads, 4x4/thread
//    TRANSB=1: C = A[M,K] * B[N,K]^T    (weights / S-gemm)
//    TRANSB=0: C = A[M,K] * B[K,N]      (PV / corr)
//    PERMB: B row n -> ((n&31)<<5)|(n>>5)    (W-major key quirk)
//    EPI: 0 plain, 1 +bias[n], 2 scale*acc + addB[row,col]
// ---------------------------------------------------------------------------
template<int TRANSB, int PERMB, int EPI>
__global__ __launch_bounds__(256) void k_gemm64(
    const float* __restrict__ A, const float* __restrict__ Bm,
    const float* __restrict__ bias, float* __restrict__ Cm,
    int M, int N, int K, size_t sA, size_t sB, size_t sC,
    const float* __restrict__ scaleP, const float* __restrict__ addB, size_t sAdd)
{
    __shared__ float As[16][64];
    __shared__ float Bs[16][64];
    int b = blockIdx.z;
    A  += (size_t)b * sA;
    Bm += (size_t)b * sB;
    Cm += (size_t)b * sC;
    int n0 = blockIdx.x * 64, m0 = blockIdx.y * 64;
    int tid = threadIdx.x;
    int tm = tid >> 4, tn = tid & 15;

    float acc[4][4];
    #pragma unroll
    for (int i = 0; i < 4; ++i)
        #pragma unroll
        for (int j = 0; j < 4; ++j) acc[i][j] = 0.f;

    for (int k0 = 0; k0 < K; k0 += 16) {
        {   // A tile: [64 rows m][16 k] -> As[k][m]
            int ar = tid >> 2, ac = (tid & 3) << 2;
            const float4 av = *(const float4*)&A[(size_t)(m0 + ar) * K + k0 + ac];
            As[ac + 0][ar] = av.x; As[ac + 1][ar] = av.y;
            As[ac + 2][ar] = av.z; As[ac + 3][ar] = av.w;
        }
        if (TRANSB) {
            int br = tid >> 2, bc = (tid & 3) << 2;
            int nrow = n0 + br;
            if (PERMB) nrow = ((nrow & 31) << 5) | (nrow >> 5);
            const float4 bv = *(const float4*)&Bm[(size_t)nrow * K + k0 + bc];
            Bs[bc + 0][br] = bv.x; Bs[bc + 1][br] = bv.y;
            Bs[bc + 2][br] = bv.z; Bs[bc + 3][br] = bv.w;
        } else {
            int kr = tid >> 4, nc = (tid & 15) << 2;
            const float4 bv = *(const float4*)&Bm[(size_t)(k0 + kr) * N + n0 + nc];
            Bs[kr][nc + 0] = bv.x; Bs[kr][nc + 1] = bv.y;
            Bs[kr][nc + 2] = bv.z; Bs[kr][nc + 3] = bv.w;
        }
        __syncthreads();
        #pragma unroll
        for (int kk = 0; kk < 16; ++kk) {
            float4 a4 = *(const float4*)&As[kk][tm << 2];
            float4 b4 = *(const float4*)&Bs[kk][tn << 2];
            float a[4] = {a4.x, a4.y, a4.z, a4.w};
            float bb[4] = {b4.x, b4.y, b4.z, b4.w};
            #pragma unroll
            for (int i = 0; i < 4; ++i)
                #pragma unroll
                for (int j = 0; j < 4; ++j)
                    acc[i][j] = fmaf(a[i], bb[j], acc[i][j]);
        }
        __syncthreads();
    }

    float scale = (EPI == 2) ? scaleP[0] : 0.f;
    #pragma unroll
    for (int i = 0; i < 4; ++i) {
        int row = m0 + (tm << 2) + i;
        #pragma unroll
        for (int j = 0; j < 4; ++j) {
            int col = n0 + (tn << 2) + j;
            float v = acc[i][j];
            if (EPI == 1) v += bias[col];
            if (EPI == 2) v = scale * v + addB[(size_t)b * sAdd + (size_t)row * N + col];
            Cm[(size_t)row * N + col] = v;
        }
    }
}

// ---------------------------------------------------------------------------
// 4) row softmax over S [16*1024, 1024]
// ---------------------------------------------------------------------------
__global__ __launch_bounds__(256) void k_softmax(float* __restrict__ S) {
    size_t row = blockIdx.x;
    float* r = S + row * (size_t)HW_;
    int t = threadIdx.x;
    float4 v = ((float4*)r)[t];

    __shared__ float redm[4], reds[4];
    int wid = t >> 6, lane = t & 63;

    float m = fmaxf(fmaxf(v.x, v.y), fmaxf(v.z, v.w));
    for (int o = 32; o > 0; o >>= 1) m = fmaxf(m, __shfl_down(m, o));
    if (lane == 0) redm[wid] = m;
    __syncthreads();
    if (t == 0) redm[0] = fmaxf(fmaxf(redm[0], redm[1]), fmaxf(redm[2], redm[3]));
    __syncthreads();
    m = redm[0];

    v.x = expf(v.x - m); v.y = expf(v.y - m);
    v.z = expf(v.z - m); v.w = expf(v.w - m);
    float s = v.x + v.y + v.z + v.w;
    for (int o = 32; o > 0; o >>= 1) s += __shfl_down(s, o);
    if (lane == 0) reds[wid] = s;
    __syncthreads();
    if (t == 0) reds[0] = reds[0] + reds[1] + reds[2] + reds[3];
    __syncthreads();
    float inv = 1.f / reds[0];
    v.x *= inv; v.y *= inv; v.z *= inv; v.w *= inv;
    ((float4*)r)[t] = v;
}

// ---------------------------------------------------------------------------
// 5) per-row top-48 (descending) + relu, via bitonic sort of 1024 in LDS
// ---------------------------------------------------------------------------
__global__ __launch_bounds__(256) void k_topk(const float* __restrict__ corr,
                                              float* __restrict__ topv) {
    size_t row = blockIdx.x;
    __shared__ float s[HW_];
    const float* r = corr + row * (size_t)HW_;
    int tid = threadIdx.x;
    #pragma unroll
    for (int e = 0; e < 4; ++e) s[tid + e * 256] = r[tid + e * 256];
    __syncthreads();
    for (int k = 2; k <= HW_; k <<= 1) {
        for (int j = k >> 1; j > 0; j >>= 1) {
            #pragma unroll
            for (int e = 0; e < 4; ++e) {
                int t = tid + e * 256;
                int ixj = t ^ j;
                if (ixj > t) {
                    float a = s[t], b2 = s[ixj];
                    bool desc = ((t & k) == 0);
                    bool sw = desc ? (a < b2) : (a > b2);
                    if (sw) { s[t] = b2; s[ixj] = a; }
                }
            }
            __syncthreads();
        }
    }
    if (tid < T_) topv[row * T_ + tid] = fmaxf(s[tid], 0.f);
}

// ---------------------------------------------------------------------------
// 6) column norm over (B,H): colss[w*T+t] = sum_{b,h} topv[b,h,w,t]^2
// ---------------------------------------------------------------------------
__global__ void k_colss(const float* __restrict__ topv, float* __restrict__ colss) {
    int o = blockIdx.x;        // w*T + t, 32*48 = 1536 blocks
    int w = o / T_, t = o % T_;
    int lane = threadIdx.x;    // 64
    float s = 0.f;
    for (int i = lane; i < 512; i += 64) {
        int b = i >> 5, h = i & 31;
        float v = topv[(size_t)((b << 10) + (h << 5) + w) * T_ + t];
        s += v * v;
    }
    for (int off = 32; off > 0; off >>= 1) s += __shfl_down(s, off);
    if (lane == 0) colss[o] = s;
}

// out[b, t, h, w] = topv[b, h, w, t] * rsqrt(colss[w, t])
__global__ void k_final(const float* __restrict__ topv, const float* __restrict__ colss,
                        float* __restrict__ out) {
    int idx = blockIdx.x * 256 + threadIdx.x;
    if (idx >= B_ * T_ * HW_) return;
    int w = idx & 31;
    int h = (idx >> 5) & 31;
    int t = (idx >> 10) % T_;
    int b = idx / (T_ * HW_);
    float v = topv[(size_t)((b << 10) + (h << 5) + w) * T_ + t];
    out[idx] = v * rsqrtf(colss[w * T_ + t]);
}

// ---------------------------------------------------------------------------
extern "C" void kernel_launch(void* const* d_in, const int* in_sizes, int n_in,
                              void* d_out, int out_size, void* d_ws, size_t ws_size,
                              hipStream_t stream) {
    const float* x     = (const float*)d_in[0];
    const float* fW    = (const float*)d_in[1];
    const float* fb    = (const float*)d_in[2];
    const float* gW    = (const float*)d_in[3];
    const float* gb    = (const float*)d_in[4];
    const float* hW    = (const float*)d_in[5];
    const float* hb    = (const float*)d_in[6];
    const float* scale = (const float*)d_in[7];
    float* out = (float*)d_out;

    float* ws   = (float*)d_ws;
    float* part = ws;                                   // 32*1024
    float* ninv = part + 32 * HW_;                      // 1024
    float* xnT  = ninv + HW_;                           // B*HW*C   (also fdd)
    float* f    = xnT + (size_t)B_ * HW_ * C_;          // B*HW*TC
    float* g    = f   + (size_t)B_ * HW_ * TC_;         // B*HW*TC
    float* hv   = g   + (size_t)B_ * HW_ * TC_;         // B*HW*C
    float* S    = hv  + (size_t)B_ * HW_ * C_;          // B*HW*HW  (also corr)
    float* topv = S   + (size_t)B_ * HW_ * HW_;         // B*HW*T
    float* colss= topv + (size_t)B_ * HW_ * T_;         // W*T
    float* fdd  = xnT;                                  // alias: epilogue reads xnT then writes same elem

    const size_t sXn = (size_t)HW_ * C_;
    const size_t sFG = (size_t)HW_ * TC_;
    const size_t sS  = (size_t)HW_ * HW_;

    // 1) per-pixel Frobenius norm
    k_colsq<<<128, 256, 0, stream>>>(x, part);
    k_rsqrt<<<4, 256, 0, stream>>>(part, ninv);

    // 2) normalized channel-last copy
    k_transpose<<<dim3(32, 16, 16), dim3(32, 8), 0, stream>>>(x, ninv, xnT);

    // 3) 1x1 convs: f, g (N=64), hv (N=512) — NT with bias
    k_gemm64<1, 0, 1><<<dim3(1, 16, 16), 256, 0, stream>>>(xnT, fW, fb, f,
        HW_, TC_, C_, sXn, 0, sFG, nullptr, nullptr, 0);
    k_gemm64<1, 0, 1><<<dim3(1, 16, 16), 256, 0, stream>>>(xnT, gW, gb, g,
        HW_, TC_, C_, sXn, 0, sFG, nullptr, nullptr, 0);
    k_gemm64<1, 0, 1><<<dim3(8, 16, 16), 256, 0, stream>>>(xnT, hW, hb, hv,
        HW_, C_, C_, sXn, 0, sXn, nullptr, nullptr, 0);

    // 4) S = f @ perm(g)^T  (K=64, keys W-major)
    k_gemm64<1, 1, 0><<<dim3(16, 16, 16), 256, 0, stream>>>(f, g, nullptr, S,
        HW_, HW_, TC_, sFG, sFG, sS, nullptr, nullptr, 0);

    // 5) row softmax
    k_softmax<<<B_ * HW_, 256, 0, stream>>>(S);

    // 6) fdd = scale * (P @ hv) + xnT   (written over xnT, safe aliasing)
    k_gemm64<0, 0, 2><<<dim3(8, 16, 16), 256, 0, stream>>>(S, hv, nullptr, fdd,
        HW_, C_, HW_, sS, sXn, sXn, scale, xnT, sXn);

    // 7) corr = fdd[1024,512] @ fdd[512,1024] (same flat buffer), into S
    k_gemm64<0, 0, 0><<<dim3(16, 16, 16), 256, 0, stream>>>(fdd, fdd, nullptr, S,
        HW_, HW_, C_, sXn, sXn, sS, nullptr, nullptr, 0);

    // 8) per-row top-48 desc + relu
    k_topk<<<B_ * HW_, 256, 0, stream>>>(S, topv);

    // 9) norm over (B,H) and final transpose
    k_colss<<<W_ * T_, 64, 0, stream>>>(topv, colss);
    k_final<<<(B_ * T_ * HW_ + 255) / 256, 256, 0, stream>>>(topv, colss, out);
}

// Round 2
// 417.928 us; speedup vs baseline: 2.4294x; 2.4294x over previous
//
#include <hip/hip_runtime.h>
#include <cstdint>
#include <cstddef>

#define B_   16
#define C_   512
#define H_   32
#define W_   32
#define HW_  1024
#define TC_  64
#define T_   48

typedef __attribute__((ext_vector_type(8))) short short8v;
typedef __attribute__((ext_vector_type(4))) float f32x4;

// ---------------------------------------------------------------------------
// packed hi/lo bf16 representation of fp32 (same 4B footprint)
// ---------------------------------------------------------------------------
__device__ __forceinline__ unsigned pack_hilo(float x) {
    unsigned u = __float_as_uint(x);
    unsigned hi = (u + 0x7FFFu + ((u >> 16) & 1u)) >> 16;     // RTNE bf16
    float hif = __uint_as_float(hi << 16);
    float lof = x - hif;
    unsigned ul = __float_as_uint(lof);
    unsigned lo = (ul + 0x7FFFu + ((ul >> 16) & 1u)) >> 16;   // RTNE bf16
    return (hi << 16) | lo;
}
__device__ __forceinline__ float unpack_hilo(unsigned w) {
    return __uint_as_float(w & 0xFFFF0000u) + __uint_as_float(w << 16);
}

__device__ __forceinline__ void gload_lds16(const unsigned* g, unsigned* l) {
    __builtin_amdgcn_global_load_lds(
        (const __attribute__((address_space(1))) void*)g,
        (__attribute__((address_space(3))) void*)l, 16, 0, 0);
}

__device__ __forceinline__ void unpack8(uint4 w0, uint4 w1, short8v& h, short8v& l) {
    h[0] = (short)(w0.x >> 16); l[0] = (short)(w0.x);
    h[1] = (short)(w0.y >> 16); l[1] = (short)(w0.y);
    h[2] = (short)(w0.z >> 16); l[2] = (short)(w0.z);
    h[3] = (short)(w0.w >> 16); l[3] = (short)(w0.w);
    h[4] = (short)(w1.x >> 16); l[4] = (short)(w1.x);
    h[5] = (short)(w1.y >> 16); l[5] = (short)(w1.y);
    h[6] = (short)(w1.z >> 16); l[6] = (short)(w1.z);
    h[7] = (short)(w1.w >> 16); l[7] = (short)(w1.w);
}

// ---------------------------------------------------------------------------
// 1) column sums of squares over (B,C): x as [8192, 1024]
// ---------------------------------------------------------------------------
__global__ void k_colsq(const float* __restrict__ x, float* __restrict__ partial) {
    int bid = blockIdx.x;
    int col = (bid & 3) * 256 + threadIdx.x;
    int r0  = (bid >> 2) * 256;
    const float* p = x + (size_t)r0 * HW_ + col;
    float s = 0.f;
    for (int r = 0; r < 256; ++r) { float v = p[(size_t)r * HW_]; s += v * v; }
    partial[(size_t)(bid >> 2) * HW_ + col] = s;
}

__global__ void k_rsqrt(const float* __restrict__ partial, float* __restrict__ ninv) {
    int i = blockIdx.x * 256 + threadIdx.x;
    if (i < HW_) {
        float s = 0.f;
        for (int r = 0; r < 32; ++r) s += partial[(size_t)r * HW_ + i];
        ninv[i] = rsqrtf(s);
    }
}

// ---------------------------------------------------------------------------
// 2) transpose + normalize: x [B,C,HW] -> xnT fp32 [B,HW,C]
// ---------------------------------------------------------------------------
__global__ void k_transpose(const float* __restrict__ x, const float* __restrict__ ninv,
                            float* __restrict__ xnT) {
    __shared__ float tile[32][33];
    int b  = blockIdx.z;
    int m0 = blockIdx.x * 32, c0 = blockIdx.y * 32;
    int tx = threadIdx.x, ty = threadIdx.y;
    const float* xb = x + (size_t)b * C_ * HW_;
    #pragma unroll
    for (int j = 0; j < 32; j += 8)
        tile[ty + j][tx] = xb[(size_t)(c0 + ty + j) * HW_ + m0 + tx];
    __syncthreads();
    float* ob = xnT + (size_t)b * HW_ * C_;
    #pragma unroll
    for (int j = 0; j < 32; j += 8) {
        int m = m0 + ty + j;
        ob[(size_t)m * C_ + c0 + tx] = tile[tx][ty + j] * ninv[m];
    }
}

// ---------------------------------------------------------------------------
// 3) pack fp32 -> hi/lo word (in place, or copy)
// ---------------------------------------------------------------------------
__global__ void k_pack(unsigned* __restrict__ buf) {
    size_t i = (size_t)blockIdx.x * 256 + threadIdx.x;
    buf[i] = pack_hilo(__uint_as_float(buf[i]));
}
__global__ void k_packc(const float* __restrict__ in, unsigned* __restrict__ out) {
    size_t i = (size_t)blockIdx.x * 256 + threadIdx.x;
    out[i] = pack_hilo(in[i]);
}

// ---------------------------------------------------------------------------
// 4) fp32 tiled GEMM (kept for f/g/S): C = A[M,K]*B[N,K]^T, opt. key-perm
// ---------------------------------------------------------------------------
template<int PERMB, int EPI>  // EPI: 0 plain, 1 +bias[n]
__global__ __launch_bounds__(256) void k_gemm64(
    const float* __restrict__ A, const float* __restrict__ Bm,
    const float* __restrict__ bias, float* __restrict__ Cm,
    int M, int N, int K, size_t sA, size_t sB, size_t sC)
{
    __shared__ float As[16][64];
    __shared__ float Bs[16][64];
    int b = blockIdx.z;
    A  += (size_t)b * sA;
    Bm += (size_t)b * sB;
    Cm += (size_t)b * sC;
    int n0 = blockIdx.x * 64, m0 = blockIdx.y * 64;
    int tid = threadIdx.x;
    int tm = tid >> 4, tn = tid & 15;

    float acc[4][4];
    #pragma unroll
    for (int i = 0; i < 4; ++i)
        #pragma unroll
        for (int j = 0; j < 4; ++j) acc[i][j] = 0.f;

    for (int k0 = 0; k0 < K; k0 += 16) {
        {
            int ar = tid >> 2, ac = (tid & 3) << 2;
            const float4 av = *(const float4*)&A[(size_t)(m0 + ar) * K + k0 + ac];
            As[ac + 0][ar] = av.x; As[ac + 1][ar] = av.y;
            As[ac + 2][ar] = av.z; As[ac + 3][ar] = av.w;
        }
        {
            int br = tid >> 2, bc = (tid & 3) << 2;
            int nrow = n0 + br;
            if (PERMB) nrow = ((nrow & 31) << 5) | (nrow >> 5);
            const float4 bv = *(const float4*)&Bm[(size_t)nrow * K + k0 + bc];
            Bs[bc + 0][br] = bv.x; Bs[bc + 1][br] = bv.y;
            Bs[bc + 2][br] = bv.z; Bs[bc + 3][br] = bv.w;
        }
        __syncthreads();
        #pragma unroll
        for (int kk = 0; kk < 16; ++kk) {
            float4 a4 = *(const float4*)&As[kk][tm << 2];
            float4 b4 = *(const float4*)&Bs[kk][tn << 2];
            float a[4] = {a4.x, a4.y, a4.z, a4.w};
            float bb[4] = {b4.x, b4.y, b4.z, b4.w};
            #pragma unroll
            for (int i = 0; i < 4; ++i)
                #pragma unroll
                for (int j = 0; j < 4; ++j)
                    acc[i][j] = fmaf(a[i], bb[j], acc[i][j]);
        }
        __syncthreads();
    }
    #pragma unroll
    for (int i = 0; i < 4; ++i) {
        int row = m0 + (tm << 2) + i;
        #pragma unroll
        for (int j = 0; j < 4; ++j) {
            int col = n0 + (tn << 2) + j;
            float v = acc[i][j];
            if (EPI == 1) v += bias[col];
            Cm[(size_t)row * N + col] = v;
        }
    }
}

// ---------------------------------------------------------------------------
// 5) split-precision bf16 MFMA GEMM: C = A[M,K] * Bt[N,K]^T, packed operands
//    128x128 tile, BK=32 words, 4 waves, global_load_lds + granule XOR swizzle
//    EPI 0: Cf fp32 = acc
//    EPI 1: Cp packed = acc + bias[row]
//    EPI 2: XnFdd packed, in place: v = scale*acc + unpack(XnFdd); write pack(v)
// ---------------------------------------------------------------------------
template<int EPI>
__global__ __launch_bounds__(256) void k_mfma(
    const unsigned* __restrict__ Ap, const unsigned* __restrict__ Btp,
    const float* __restrict__ bias,
    float* __restrict__ Cf, unsigned* __restrict__ Cp,
    const float* __restrict__ scaleP, unsigned* __restrict__ XnFdd,
    int N, int K, long sA, long sB, long sC)
{
    __shared__ unsigned Asm[128 * 32];
    __shared__ unsigned Bsm[128 * 32];
    const int b = blockIdx.z;
    const unsigned* Ab = Ap  + (size_t)b * sA;
    const unsigned* Bb = Btp + (size_t)b * sB;
    const int m0 = blockIdx.y * 128, n0 = blockIdx.x * 128;
    const int tid = threadIdx.x, wave = tid >> 6, lane = tid & 63;
    const int wm = wave >> 1, wn = wave & 1;

    f32x4 acc[4][4];
    #pragma unroll
    for (int i = 0; i < 4; ++i)
        #pragma unroll
        for (int j = 0; j < 4; ++j) { f32x4 z = {0.f, 0.f, 0.f, 0.f}; acc[i][j] = z; }

    const int g = lane >> 4;           // k-group for fragments
    const int nkt = K >> 5;

    for (int kt = 0; kt < nkt; ++kt) {
        const int k0 = kt << 5;
        __syncthreads();
        #pragma unroll
        for (int li = 0; li < 4; ++li) {
            int row = wave * 32 + li * 8 + (lane >> 3);
            int gr  = (lane & 7) ^ (row & 7);          // pre-swizzled global granule
            gload_lds16(Ab + (size_t)(m0 + row) * K + k0 + gr * 4,
                        &Asm[(wave * 32 + li * 8) * 32]);
            gload_lds16(Bb + (size_t)(n0 + row) * K + k0 + gr * 4,
                        &Bsm[(wave * 32 + li * 8) * 32]);
        }
        __syncthreads();

        short8v ah[4], al[4];
        #pragma unroll
        for (int i = 0; i < 4; ++i) {
            int r = wm * 64 + i * 16 + (lane & 15);
            const unsigned* p = &Asm[r * 32];
            uint4 w0 = *(const uint4*)&p[(((2 * g)     ^ (r & 7)) << 2)];
            uint4 w1 = *(const uint4*)&p[(((2 * g + 1) ^ (r & 7)) << 2)];
            unpack8(w0, w1, ah[i], al[i]);
        }
        #pragma unroll
        for (int j = 0; j < 4; ++j) {
            int r = wn * 64 + j * 16 + (lane & 15);
            const unsigned* p = &Bsm[r * 32];
            uint4 w0 = *(const uint4*)&p[(((2 * g)     ^ (r & 7)) << 2)];
            uint4 w1 = *(const uint4*)&p[(((2 * g + 1) ^ (r & 7)) << 2)];
            short8v bh, bl;
            unpack8(w0, w1, bh, bl);
            #pragma unroll
            for (int i = 0; i < 4; ++i) {
                acc[i][j] = __builtin_amdgcn_mfma_f32_16x16x32_bf16(ah[i], bh, acc[i][j], 0, 0, 0);
                acc[i][j] = __builtin_amdgcn_mfma_f32_16x16x32_bf16(ah[i], bl, acc[i][j], 0, 0, 0);
                acc[i][j] = __builtin_amdgcn_mfma_f32_16x16x32_bf16(al[i], bh, acc[i][j], 0, 0, 0);
            }
        }
    }

    const int colbase = n0 + wn * 64 + (lane & 15);
    const int rowbase = m0 + wm * 64 + ((lane >> 4) << 2);
    if (EPI == 0) {
        float* Co = Cf + (size_t)b * sC;
        #pragma unroll
        for (int i = 0; i < 4; ++i)
            #pragma unroll
            for (int j = 0; j < 4; ++j) {
                int col = colbase + j * 16;
                #pragma unroll
                for (int rg = 0; rg < 4; ++rg)
                    Co[(size_t)(rowbase + i * 16 + rg) * N + col] = acc[i][j][rg];
            }
    } else if (EPI == 1) {
        unsigned* Co = Cp + (size_t)b * sC;
        #pragma unroll
        for (int i = 0; i < 4; ++i)
            #pragma unroll
            for (int j = 0; j < 4; ++j) {
                int col = colbase + j * 16;
                #pragma unroll
                for (int rg = 0; rg < 4; ++rg) {
                    int row = rowbase + i * 16 + rg;
                    Co[(size_t)row * N + col] = pack_hilo(acc[i][j][rg] + bias[row]);
                }
            }
    } else {
        float sc = scaleP[0];
        unsigned* Xn = XnFdd + (size_t)b * sC;
        #pragma unroll
        for (int i = 0; i < 4; ++i)
            #pragma unroll
            for (int j = 0; j < 4; ++j) {
                int col = colbase + j * 16;
                #pragma unroll
                for (int rg = 0; rg < 4; ++rg) {
                    size_t idx = (size_t)(rowbase + i * 16 + rg) * N + col;
                    float xv = unpack_hilo(Xn[idx]);
                    Xn[idx] = pack_hilo(sc * acc[i][j][rg] + xv);
                }
            }
    }
}

// ---------------------------------------------------------------------------
// 6) row softmax over S [16*1024,1024] fp32 -> write packed hi/lo in place
// ---------------------------------------------------------------------------
__global__ __launch_bounds__(256) void k_softmax(float* __restrict__ S) {
    size_t row = blockIdx.x;
    float* r = S + row * (size_t)HW_;
    int t = threadIdx.x;
    float4 v = ((float4*)r)[t];

    __shared__ float redm[4], reds[4];
    int wid = t >> 6, lane = t & 63;

    float m = fmaxf(fmaxf(v.x, v.y), fmaxf(v.z, v.w));
    for (int o = 32; o > 0; o >>= 1) m = fmaxf(m, __shfl_down(m, o));
    if (lane == 0) redm[wid] = m;
    __syncthreads();
    if (t == 0) redm[0] = fmaxf(fmaxf(redm[0], redm[1]), fmaxf(redm[2], redm[3]));
    __syncthreads();
    m = redm[0];

    v.x = expf(v.x - m); v.y = expf(v.y - m);
    v.z = expf(v.z - m); v.w = expf(v.w - m);
    float s = v.x + v.y + v.z + v.w;
    for (int o = 32; o > 0; o >>= 1) s += __shfl_down(s, o);
    if (lane == 0) reds[wid] = s;
    __syncthreads();
    if (t == 0) reds[0] = reds[0] + reds[1] + reds[2] + reds[3];
    __syncthreads();
    float inv = 1.f / reds[0];
    uint4 pw;
    pw.x = pack_hilo(v.x * inv); pw.y = pack_hilo(v.y * inv);
    pw.z = pack_hilo(v.z * inv); pw.w = pack_hilo(v.w * inv);
    ((uint4*)r)[t] = pw;
}

// ---------------------------------------------------------------------------
// 7) uint32 transpose: in [R,Cc] per batch -> out [Cc,R]
// ---------------------------------------------------------------------------
__global__ void k_tpose32(const unsigned* __restrict__ in, unsigned* __restrict__ out,
                          int R, int Cc) {
    __shared__ unsigned tile[32][33];
    int b = blockIdx.z;
    const unsigned* ib = in + (size_t)b * R * Cc;
    unsigned* ob = out + (size_t)b * R * Cc;
    int c0 = blockIdx.x * 32, r0 = blockIdx.y * 32;
    int tx = threadIdx.x, ty = threadIdx.y;
    #pragma unroll
    for (int j = 0; j < 32; j += 8)
        tile[ty + j][tx] = ib[(size_t)(r0 + ty + j) * Cc + c0 + tx];
    __syncthreads();
    #pragma unroll
    for (int j = 0; j < 32; j += 8)
        ob[(size_t)(c0 + ty + j) * R + r0 + tx] = tile[tx][ty + j];
}

// ---------------------------------------------------------------------------
// 8) per-row top-48 via wave bitonic sort-64 + top-64 merges (no big LDS sort)
// ---------------------------------------------------------------------------
__device__ __forceinline__ float bmerge64_desc(float a, float b, int lane) {
    float br = __shfl(b, 63 - lane);
    float c = fmaxf(a, br);                       // top-64 of union, bitonic
    #pragma unroll
    for (int j = 32; j > 0; j >>= 1) {
        float o = __shfl_xor(c, j);
        c = ((lane & j) == 0) ? fmaxf(c, o) : fminf(c, o);
    }
    return c;                                     // sorted descending
}

__global__ __launch_bounds__(256) void k_topk(const float* __restrict__ corr,
                                              float* __restrict__ topv) {
    int row = blockIdx.x;
    int tid = threadIdx.x, wave = tid >> 6, lane = tid & 63;
    const float* r = corr + (size_t)row * HW_;
    float v[4];
    #pragma unroll
    for (int c = 0; c < 4; ++c) v[c] = r[wave * 256 + c * 64 + lane];

    // sort each 64-chunk descending (4 chunks interleaved for ILP)
    #pragma unroll
    for (int k = 2; k <= 64; k <<= 1) {
        #pragma unroll
        for (int j = k >> 1; j > 0; j >>= 1) {
            bool upbit = (lane & k) == 0;
            bool lower = (lane & j) == 0;
            bool takeMax = (upbit == lower);
            #pragma unroll
            for (int c = 0; c < 4; ++c) {
                float o = __shfl_xor(v[c], j);
                v[c] = takeMax ? fmaxf(v[c], o) : fminf(v[c], o);
            }
        }
    }
    float m01 = bmerge64_desc(v[0], v[1], lane);
    float m23 = bmerge64_desc(v[2], v[3], lane);
    float mw  = bmerge64_desc(m01, m23, lane);

    __shared__ float ls[4][64];
    ls[wave][lane] = mw;
    __syncthreads();
    if (wave == 0) {
        float e  = bmerge64_desc(ls[0][lane], ls[1][lane], lane);
        float f2 = bmerge64_desc(ls[2][lane], ls[3][lane], lane);
        float g2 = bmerge64_desc(e, f2, lane);
        if (lane < T_) topv[(size_t)row * T_ + lane] = fmaxf(g2, 0.f);
    }
}

// ---------------------------------------------------------------------------
// 9) column norm over (B,H) and final transpose
// ---------------------------------------------------------------------------
__global__ void k_colss(const float* __restrict__ topv, float* __restrict__ colss) {
    int o = blockIdx.x;
    int w = o / T_, t = o % T_;
    int lane = threadIdx.x;
    float s = 0.f;
    for (int i = lane; i < 512; i += 64) {
        int b = i >> 5, h = i & 31;
        float v = topv[(size_t)((b << 10) + (h << 5) + w) * T_ + t];
        s += v * v;
    }
    for (int off = 32; off > 0; off >>= 1) s += __shfl_down(s, off);
    if (lane == 0) colss[o] = s;
}

__global__ void k_final(const float* __restrict__ topv, const float* __restrict__ colss,
                        float* __restrict__ out) {
    int idx = blockIdx.x * 256 + threadIdx.x;
    if (idx >= B_ * T_ * HW_) return;
    int w = idx & 31;
    int h = (idx >> 5) & 31;
    int t = (idx >> 10) % T_;
    int b = idx / (T_ * HW_);
    float v = topv[(size_t)((b << 10) + (h << 5) + w) * T_ + t];
    out[idx] = v * rsqrtf(colss[w * T_ + t]);
}

// ---------------------------------------------------------------------------
extern "C" void kernel_launch(void* const* d_in, const int* in_sizes, int n_in,
                              void* d_out, int out_size, void* d_ws, size_t ws_size,
                              hipStream_t stream) {
    const float* x     = (const float*)d_in[0];
    const float* fW    = (const float*)d_in[1];
    const float* fb    = (const float*)d_in[2];
    const float* gW    = (const float*)d_in[3];
    const float* gb    = (const float*)d_in[4];
    const float* hW    = (const float*)d_in[5];
    const float* hb    = (const float*)d_in[6];
    const float* scale = (const float*)d_in[7];
    float* out = (float*)d_out;

    // workspace layout (4B words), total ~137.1 MB
    float*    ws   = (float*)d_ws;
    float*    part = ws;                                  // 32768
    float*    ninv = part + 32 * HW_;                     // 1024
    unsigned* hWp  = (unsigned*)(ninv + HW_);             // 262144
    float*    xnT  = (float*)(hWp + C_ * C_);             // 8388608  fp32 -> packed xn -> packed fdd
    float*    f    = xnT + (size_t)B_ * HW_ * C_;         // 1048576  (later: topv)
    float*    g    = f + (size_t)B_ * HW_ * TC_;          // 1048576  (later: colss)
    unsigned* hvT  = (unsigned*)(g + (size_t)B_ * HW_ * TC_); // 8388608  hvT packed -> fddBt packed
    float*    S    = (float*)(hvT + (size_t)B_ * C_ * HW_);   // 16777216 S fp32 -> P packed -> corr fp32
    float*    topv = f;
    float*    colss= g;

    const size_t sXn  = (size_t)HW_ * C_;    // 524288
    const size_t sFG  = (size_t)HW_ * TC_;
    const size_t sHvT = (size_t)C_ * HW_;    // 524288
    const size_t sS   = (size_t)HW_ * HW_;   // 1048576

    // 1) Frobenius norm over (B,C) per pixel
    k_colsq<<<128, 256, 0, stream>>>(x, part);
    k_rsqrt<<<4, 256, 0, stream>>>(part, ninv);

    // 2) normalized channel-last fp32 copy
    k_transpose<<<dim3(32, 16, 16), dim3(32, 8), 0, stream>>>(x, ninv, xnT);

    // 3) f,g projections in fp32 (read xnT before it gets packed)
    k_gemm64<0, 1><<<dim3(1, 16, 16), 256, 0, stream>>>(xnT, fW, fb, f,
        HW_, TC_, C_, sXn, 0, sFG);
    k_gemm64<0, 1><<<dim3(1, 16, 16), 256, 0, stream>>>(xnT, gW, gb, g,
        HW_, TC_, C_, sXn, 0, sFG);

    // 4) pack xn (in place) and hW (copy)
    k_pack<<<(B_ * sXn) / 256, 256, 0, stream>>>((unsigned*)xnT);
    k_packc<<<(C_ * C_) / 256, 256, 0, stream>>>(hW, hWp);

    // 5) hvT = hW @ xn^T  (direct transposed h: rows=c, cols=hw), packed out
    k_mfma<1><<<dim3(HW_ / 128, C_ / 128, B_), 256, 0, stream>>>(
        hWp, (const unsigned*)xnT, hb, nullptr, hvT, nullptr, nullptr,
        HW_, C_, 0, (long)sXn, (long)sHvT);

    // 6) S = f @ perm(g)^T  (fp32, W-major keys)
    k_gemm64<1, 0><<<dim3(16, 16, 16), 256, 0, stream>>>(f, g, nullptr, S,
        HW_, HW_, TC_, sFG, sFG, sS);

    // 7) softmax rows -> P packed in place
    k_softmax<<<B_ * HW_, 256, 0, stream>>>(S);

    // 8) fdd = scale*(P @ hv) + xn, packed, in place over xn
    k_mfma<2><<<dim3(C_ / 128, HW_ / 128, B_), 256, 0, stream>>>(
        (const unsigned*)S, hvT, nullptr, nullptr, nullptr, scale, (unsigned*)xnT,
        C_, HW_, (long)sS, (long)sHvT, (long)sXn);

    // 9) fddBt[n,k] = fdd_flat[k*1024+n]  (uint32 transpose of [512,1024] view)
    k_tpose32<<<dim3(32, 16, 16), dim3(32, 8), 0, stream>>>(
        (const unsigned*)xnT, hvT, C_, HW_);

    // 10) corr = fddA @ fddBt^T -> fp32 into S region
    k_mfma<0><<<dim3(HW_ / 128, HW_ / 128, B_), 256, 0, stream>>>(
        (const unsigned*)xnT, hvT, nullptr, S, nullptr, nullptr, nullptr,
        HW_, C_, (long)sXn, (long)sXn, (long)sS);

    // 11) top-48 desc + relu
    k_topk<<<B_ * HW_, 256, 0, stream>>>(S, topv);

    // 12) norm over (B,H) + output transpose
    k_colss<<<W_ * T_, 64, 0, stream>>>(topv, colss);
    k_final<<<(B_ * T_ * HW_ + 255) / 256, 256, 0, stream>>>(topv, colss, out);
}

// Round 3
// 348.698 us; speedup vs baseline: 2.9117x; 1.1985x over previous
//
#include <hip/hip_runtime.h>
#include <cstdint>
#include <cstddef>

#define B_   16
#define C_   512
#define H_   32
#define W_   32
#define HW_  1024
#define TC_  64
#define T_   48

typedef unsigned short u16;
typedef __attribute__((ext_vector_type(8))) short short8v;
typedef __attribute__((ext_vector_type(4))) float f32x4;

// ---------------------------------------------------------------------------
// hi/lo bf16 split of fp32
// ---------------------------------------------------------------------------
__device__ __forceinline__ unsigned pack_hilo(float x) {
    unsigned u = __float_as_uint(x);
    unsigned hi = (u + 0x7FFFu + ((u >> 16) & 1u)) >> 16;     // RTNE bf16
    float hif = __uint_as_float(hi << 16);
    float lof = x - hif;
    unsigned ul = __float_as_uint(lof);
    unsigned lo = (ul + 0x7FFFu + ((ul >> 16) & 1u)) >> 16;   // RTNE bf16
    return (hi << 16) | lo;
}
__device__ __forceinline__ float compose_hilo(u16 hi, u16 lo) {
    return __uint_as_float(((unsigned)hi) << 16) + __uint_as_float(((unsigned)lo) << 16);
}

__device__ __forceinline__ void gld16(const void* g, void* l) {
    __builtin_amdgcn_global_load_lds(
        (const __attribute__((address_space(1))) void*)g,
        (__attribute__((address_space(3))) void*)l, 16, 0, 0);
}

__device__ __forceinline__ void unpack8(uint4 w0, uint4 w1, short8v& h, short8v& l) {
    h[0] = (short)(w0.x >> 16); l[0] = (short)(w0.x);
    h[1] = (short)(w0.y >> 16); l[1] = (short)(w0.y);
    h[2] = (short)(w0.z >> 16); l[2] = (short)(w0.z);
    h[3] = (short)(w0.w >> 16); l[3] = (short)(w0.w);
    h[4] = (short)(w1.x >> 16); l[4] = (short)(w1.x);
    h[5] = (short)(w1.y >> 16); l[5] = (short)(w1.y);
    h[6] = (short)(w1.z >> 16); l[6] = (short)(w1.z);
    h[7] = (short)(w1.w >> 16); l[7] = (short)(w1.w);
}

// ---------------------------------------------------------------------------
// 1) Frobenius-norm helpers
// ---------------------------------------------------------------------------
__global__ void k_colsq(const float* __restrict__ x, float* __restrict__ partial) {
    int bid = blockIdx.x;
    int col = (bid & 3) * 256 + threadIdx.x;
    int r0  = (bid >> 2) * 256;
    const float* p = x + (size_t)r0 * HW_ + col;
    float s = 0.f;
    for (int r = 0; r < 256; ++r) { float v = p[(size_t)r * HW_]; s += v * v; }
    partial[(size_t)(bid >> 2) * HW_ + col] = s;
}

__global__ void k_rsqrt(const float* __restrict__ partial, float* __restrict__ ninv) {
    int i = blockIdx.x * 256 + threadIdx.x;
    if (i < HW_) {
        float s = 0.f;
        for (int r = 0; r < 32; ++r) s += partial[(size_t)r * HW_ + i];
        ninv[i] = rsqrtf(s);
    }
}

// ---------------------------------------------------------------------------
// 2) transpose + normalize + split: x [B,C,HW] -> xn planes [B,HW,C] bf16 hi/lo
// ---------------------------------------------------------------------------
__global__ void k_transpose(const float* __restrict__ x, const float* __restrict__ ninv,
                            u16* __restrict__ obH, u16* __restrict__ obL) {
    __shared__ float tile[32][33];
    int b  = blockIdx.z;
    int m0 = blockIdx.x * 32, c0 = blockIdx.y * 32;
    int tx = threadIdx.x, ty = threadIdx.y;
    const float* xb = x + (size_t)b * C_ * HW_;
    #pragma unroll
    for (int j = 0; j < 32; j += 8)
        tile[ty + j][tx] = xb[(size_t)(c0 + ty + j) * HW_ + m0 + tx];
    __syncthreads();
    size_t base = (size_t)b * HW_ * C_;
    #pragma unroll
    for (int j = 0; j < 32; j += 8) {
        int m = m0 + ty + j;
        unsigned pk = pack_hilo(tile[tx][ty + j] * ninv[m]);
        size_t idx = base + (size_t)m * C_ + c0 + tx;
        obH[idx] = (u16)(pk >> 16);
        obL[idx] = (u16)pk;
    }
}

// ---------------------------------------------------------------------------
// 3) weight prep: hW planes; fgW = concat(fW,gW) planes + fgb
// ---------------------------------------------------------------------------
__global__ void k_packW(const float* __restrict__ in, u16* __restrict__ oh,
                        u16* __restrict__ ol) {
    size_t i = (size_t)blockIdx.x * 256 + threadIdx.x;
    unsigned pk = pack_hilo(in[i]);
    oh[i] = (u16)(pk >> 16); ol[i] = (u16)pk;
}
__global__ void k_packFG(const float* __restrict__ fW, const float* __restrict__ gW,
                         const float* __restrict__ fb, const float* __restrict__ gb,
                         u16* __restrict__ oh, u16* __restrict__ ol,
                         float* __restrict__ fgb) {
    int idx = blockIdx.x * 256 + threadIdx.x;   // 65536
    int row = idx >> 9, c = idx & 511;
    float v = (row < 64) ? fW[row * 512 + c] : gW[(row - 64) * 512 + c];
    unsigned pk = pack_hilo(v);
    oh[idx] = (u16)(pk >> 16); ol[idx] = (u16)pk;
    if (idx < 128) fgb[idx] = (idx < 64) ? fb[idx] : gb[idx - 64];
}

// ---------------------------------------------------------------------------
// 4) planar split-bf16 MFMA GEMM: C = A[M,K] * B[N,K]^T (+3-term split)
//    128x128 tile, BK=32 elems, 4 waves. LDS swizzle: byte = rp*128 +
//    ((gg ^ (rp&7))*16), rp=row>>1, gg=(row&1)*4+granule. Staged linearly via
//    pre-swizzled global source (global_load_lds dest = base + lane*16).
//    EPI 0: Cf fp32 = acc
//    EPI 1: planar out = acc + bias[row]
//    EPI 3: planar out = acc + bias[col]
// ---------------------------------------------------------------------------
template<int PERMB, int EPI>
__global__ __launch_bounds__(256) void k_mfmaP(
    const u16* __restrict__ Ah, const u16* __restrict__ Al,
    const u16* __restrict__ Bh, const u16* __restrict__ Bl,
    const float* __restrict__ bias,
    float* __restrict__ Cf, u16* __restrict__ Ch, u16* __restrict__ Cl,
    int N, int K, int lda, int ldb,
    long sA, long sB, long sC)
{
    __shared__ u16 AsH[4096], AsL[4096], BsH[4096], BsL[4096];  // 4 x 8KB
    const int b = blockIdx.z;
    const u16* pAh = Ah + (size_t)b * sA;
    const u16* pAl = Al + (size_t)b * sA;
    const u16* pBh = Bh + (size_t)b * sB;
    const u16* pBl = Bl + (size_t)b * sB;
    const int m0 = blockIdx.y * 128, n0 = blockIdx.x * 128;
    const int tid = threadIdx.x, wave = tid >> 6, lane = tid & 63;
    const int wm = wave >> 1, wn = wave & 1;
    const int g = lane >> 4;

    f32x4 acc[4][4];
    #pragma unroll
    for (int i = 0; i < 4; ++i)
        #pragma unroll
        for (int j = 0; j < 4; ++j) { f32x4 z = {0.f,0.f,0.f,0.f}; acc[i][j] = z; }

    // per-wave plane assignment for staging: w0->AsH w1->AsL w2->BsH w3->BsL
    const u16* gplane = (wave == 0) ? pAh : (wave == 1) ? pAl : (wave == 2) ? pBh : pBl;
    u16* lplane = (wave == 0) ? AsH : (wave == 1) ? AsL : (wave == 2) ? BsH : BsL;
    const int ld  = (wave < 2) ? lda : ldb;
    const int rb  = (wave < 2) ? m0 : n0;

    for (int kt = 0; kt < (K >> 5); ++kt) {
        const int k0 = kt << 5;
        __syncthreads();
        #pragma unroll
        for (int li = 0; li < 8; ++li) {
            int rp  = li * 8 + (lane >> 3);
            int gg  = (lane & 7) ^ (rp & 7);
            int r   = rp * 2 + (gg >> 2);
            int kc  = k0 + (gg & 3) * 8;
            int rowg = rb + r;
            if (PERMB && wave >= 2) rowg = ((rowg & 31) << 5) | (rowg >> 5);
            gld16(gplane + (size_t)rowg * ld + kc, lplane + li * 512 + lane * 8);
        }
        __syncthreads();

        short8v ah[4], al[4];
        #pragma unroll
        for (int i = 0; i < 4; ++i) {
            int r = wm * 64 + i * 16 + (lane & 15);
            int rp = r >> 1, gg = ((r & 1) << 2) + g;
            int off = rp * 64 + ((gg ^ (rp & 7)) << 3);
            ah[i] = *(const short8v*)(AsH + off);
            al[i] = *(const short8v*)(AsL + off);
        }
        #pragma unroll
        for (int j = 0; j < 4; ++j) {
            int r = wn * 64 + j * 16 + (lane & 15);
            int rp = r >> 1, gg = ((r & 1) << 2) + g;
            int off = rp * 64 + ((gg ^ (rp & 7)) << 3);
            short8v bh = *(const short8v*)(BsH + off);
            short8v bl = *(const short8v*)(BsL + off);
            #pragma unroll
            for (int i = 0; i < 4; ++i) {
                acc[i][j] = __builtin_amdgcn_mfma_f32_16x16x32_bf16(ah[i], bh, acc[i][j], 0, 0, 0);
                acc[i][j] = __builtin_amdgcn_mfma_f32_16x16x32_bf16(ah[i], bl, acc[i][j], 0, 0, 0);
                acc[i][j] = __builtin_amdgcn_mfma_f32_16x16x32_bf16(al[i], bh, acc[i][j], 0, 0, 0);
            }
        }
    }

    const int colbase = n0 + wn * 64 + (lane & 15);
    const int rowbase = m0 + wm * 64 + ((lane >> 4) << 2);
    #pragma unroll
    for (int i = 0; i < 4; ++i)
        #pragma unroll
        for (int j = 0; j < 4; ++j) {
            int col = colbase + j * 16;
            #pragma unroll
            for (int rg = 0; rg < 4; ++rg) {
                int row = rowbase + i * 16 + rg;
                size_t idx = (size_t)b * sC + (size_t)row * N + col;
                if (EPI == 0) {
                    Cf[idx] = acc[i][j][rg];
                } else {
                    float v = acc[i][j][rg] + ((EPI == 1) ? bias[row] : bias[col]);
                    unsigned pk = pack_hilo(v);
                    Ch[idx] = (u16)(pk >> 16); Cl[idx] = (u16)pk;
                }
            }
        }
}

// ---------------------------------------------------------------------------
// 5) PV GEMM: A = packed P words, B = planar hvT; epilogue:
//    fdd = scale*acc + xn (planar, in place over xn planes)
// ---------------------------------------------------------------------------
__global__ __launch_bounds__(256) void k_mfmaPV(
    const unsigned* __restrict__ P, const u16* __restrict__ Bh, const u16* __restrict__ Bl,
    u16* __restrict__ Xh, u16* __restrict__ Xl, const float* __restrict__ scaleP,
    int N, int K, int lda, int ldb, long sA, long sB, long sC)
{
    __shared__ unsigned Asm[4096];           // 16KB: 128 rows x 32 words
    __shared__ u16 BsH[4096], BsL[4096];     // 8KB each
    const int b = blockIdx.z;
    const unsigned* pA = P + (size_t)b * sA;
    const u16* pBh = Bh + (size_t)b * sB;
    const u16* pBl = Bl + (size_t)b * sB;
    const int m0 = blockIdx.y * 128, n0 = blockIdx.x * 128;
    const int tid = threadIdx.x, wave = tid >> 6, lane = tid & 63;
    const int wm = wave >> 1, wn = wave & 1;
    const int g = lane >> 4;

    f32x4 acc[4][4];
    #pragma unroll
    for (int i = 0; i < 4; ++i)
        #pragma unroll
        for (int j = 0; j < 4; ++j) { f32x4 z = {0.f,0.f,0.f,0.f}; acc[i][j] = z; }

    const u16* gbp = (wave >> 1) ? pBl : pBh;
    u16* lbp = (wave >> 1) ? BsL : BsH;

    for (int kt = 0; kt < (K >> 5); ++kt) {
        const int k0 = kt << 5;
        __syncthreads();
        #pragma unroll
        for (int li = 0; li < 4; ++li) {            // A packed: 1KB chunks
            int row = wave * 32 + li * 8 + (lane >> 3);
            int gr = (lane & 7) ^ (row & 7);
            gld16(pA + (size_t)(m0 + row) * lda + k0 + gr * 4,
                  &Asm[(wave * 32 + li * 8) * 32]);
        }
        #pragma unroll
        for (int li = 0; li < 4; ++li) {            // B planar
            int cip = ((wave & 1) << 2) + li;
            int rp = cip * 8 + (lane >> 3);
            int gg = (lane & 7) ^ (rp & 7);
            int r = rp * 2 + (gg >> 2);
            int kc = k0 + (gg & 3) * 8;
            gld16(gbp + (size_t)(n0 + r) * ldb + kc, lbp + cip * 512 + lane * 8);
        }
        __syncthreads();

        short8v ah[4], al[4];
        #pragma unroll
        for (int i = 0; i < 4; ++i) {
            int r = wm * 64 + i * 16 + (lane & 15);
            const unsigned* p = &Asm[r * 32];
            uint4 w0 = *(const uint4*)&p[(((2 * g)     ^ (r & 7)) << 2)];
            uint4 w1 = *(const uint4*)&p[(((2 * g + 1) ^ (r & 7)) << 2)];
            unpack8(w0, w1, ah[i], al[i]);
        }
        #pragma unroll
        for (int j = 0; j < 4; ++j) {
            int r = wn * 64 + j * 16 + (lane & 15);
            int rp = r >> 1, gg = ((r & 1) << 2) + g;
            int off = rp * 64 + ((gg ^ (rp & 7)) << 3);
            short8v bh = *(const short8v*)(BsH + off);
            short8v bl = *(const short8v*)(BsL + off);
            #pragma unroll
            for (int i = 0; i < 4; ++i) {
                acc[i][j] = __builtin_amdgcn_mfma_f32_16x16x32_bf16(ah[i], bh, acc[i][j], 0, 0, 0);
                acc[i][j] = __builtin_amdgcn_mfma_f32_16x16x32_bf16(ah[i], bl, acc[i][j], 0, 0, 0);
                acc[i][j] = __builtin_amdgcn_mfma_f32_16x16x32_bf16(al[i], bh, acc[i][j], 0, 0, 0);
            }
        }
    }

    float sc = scaleP[0];
    const int colbase = n0 + wn * 64 + (lane & 15);
    const int rowbase = m0 + wm * 64 + ((lane >> 4) << 2);
    #pragma unroll
    for (int i = 0; i < 4; ++i)
        #pragma unroll
        for (int j = 0; j < 4; ++j) {
            int col = colbase + j * 16;
            #pragma unroll
            for (int rg = 0; rg < 4; ++rg) {
                int row = rowbase + i * 16 + rg;
                size_t idx = (size_t)b * sC + (size_t)row * N + col;
                float v = sc * acc[i][j][rg] + compose_hilo(Xh[idx], Xl[idx]);
                unsigned pk = pack_hilo(v);
                Xh[idx] = (u16)(pk >> 16); Xl[idx] = (u16)pk;
            }
        }
}

// ---------------------------------------------------------------------------
// 6) row softmax over S fp32 -> packed hi/lo words in place
// ---------------------------------------------------------------------------
__global__ __launch_bounds__(256) void k_softmax(float* __restrict__ S) {
    size_t row = blockIdx.x;
    float* r = S + row * (size_t)HW_;
    int t = threadIdx.x;
    float4 v = ((float4*)r)[t];

    __shared__ float redm[4], reds[4];
    int wid = t >> 6, lane = t & 63;

    float m = fmaxf(fmaxf(v.x, v.y), fmaxf(v.z, v.w));
    for (int o = 32; o > 0; o >>= 1) m = fmaxf(m, __shfl_down(m, o));
    if (lane == 0) redm[wid] = m;
    __syncthreads();
    if (t == 0) redm[0] = fmaxf(fmaxf(redm[0], redm[1]), fmaxf(redm[2], redm[3]));
    __syncthreads();
    m = redm[0];

    v.x = expf(v.x - m); v.y = expf(v.y - m);
    v.z = expf(v.z - m); v.w = expf(v.w - m);
    float s = v.x + v.y + v.z + v.w;
    for (int o = 32; o > 0; o >>= 1) s += __shfl_down(s, o);
    if (lane == 0) reds[wid] = s;
    __syncthreads();
    if (t == 0) reds[0] = reds[0] + reds[1] + reds[2] + reds[3];
    __syncthreads();
    float inv = 1.f / reds[0];
    uint4 pw;
    pw.x = pack_hilo(v.x * inv); pw.y = pack_hilo(v.y * inv);
    pw.z = pack_hilo(v.z * inv); pw.w = pack_hilo(v.w * inv);
    ((uint4*)r)[t] = pw;
}

// ---------------------------------------------------------------------------
// 7) ushort transpose of the [512][1024] flat view of fdd planes -> fddT planes
// ---------------------------------------------------------------------------
__global__ void k_tposeU(const u16* __restrict__ srcH, const u16* __restrict__ srcL,
                         u16* __restrict__ dstH, u16* __restrict__ dstL) {
    __shared__ u16 tile[32][33];
    int z = blockIdx.z, b = z >> 1;
    const u16* src = ((z & 1) ? srcL : srcH) + (size_t)b * (C_ * HW_);
    u16* dst = ((z & 1) ? dstL : dstH) + (size_t)b * (C_ * HW_);
    int c0 = blockIdx.x * 32, r0 = blockIdx.y * 32;     // src [512 r][1024 c]
    int tx = threadIdx.x, ty = threadIdx.y;
    #pragma unroll
    for (int j = 0; j < 32; j += 8)
        tile[ty + j][tx] = src[(size_t)(r0 + ty + j) * HW_ + c0 + tx];
    __syncthreads();
    #pragma unroll
    for (int j = 0; j < 32; j += 8)
        dst[(size_t)(c0 + ty + j) * C_ + r0 + tx] = tile[tx][ty + j];
}

// ---------------------------------------------------------------------------
// 8) top-48: tau-prune (48th largest of 256 group-maxima) + compact + sort
// ---------------------------------------------------------------------------
__device__ __forceinline__ float sort64_desc(float v, int lane) {
    #pragma unroll
    for (int k = 2; k <= 64; k <<= 1) {
        #pragma unroll
        for (int j = k >> 1; j > 0; j >>= 1) {
            float o = __shfl_xor(v, j);
            bool takeMax = (((lane & k) == 0) == ((lane & j) == 0));
            v = takeMax ? fmaxf(v, o) : fminf(v, o);
        }
    }
    return v;
}
__device__ __forceinline__ float bmerge64_desc(float a, float b, int lane) {
    float br = __shfl(b, 63 - lane);
    float c = fmaxf(a, br);
    #pragma unroll
    for (int j = 32; j > 0; j >>= 1) {
        float o = __shfl_xor(c, j);
        c = ((lane & j) == 0) ? fmaxf(c, o) : fminf(c, o);
    }
    return c;
}

__global__ __launch_bounds__(256) void k_topk(const float* __restrict__ corr,
                                              float* __restrict__ topv) {
    int row = blockIdx.x, tid = threadIdx.x, wave = tid >> 6, lane = tid & 63;
    const float4 e = ((const float4*)(corr + (size_t)row * HW_))[tid];
    float gm = fmaxf(fmaxf(e.x, e.y), fmaxf(e.z, e.w));
    float v = sort64_desc(gm, lane);

    __shared__ float ls[4][64];
    __shared__ float tau_s;
    __shared__ int cnt_s;
    __shared__ float buf[1024];
    ls[wave][lane] = v;
    buf[tid] = -INFINITY; buf[tid + 256] = -INFINITY;
    buf[tid + 512] = -INFINITY; buf[tid + 768] = -INFINITY;
    if (tid == 0) cnt_s = 0;
    __syncthreads();

    if (wave == 0) {
        float ab = bmerge64_desc(ls[0][lane], ls[1][lane], lane);
        float cd = bmerge64_desc(ls[2][lane], ls[3][lane], lane);
        float t  = bmerge64_desc(ab, cd, lane);
        if (lane == T_ - 1) tau_s = t;      // 48th largest group-max
    }
    __syncthreads();
    float tau = tau_s;

    int c = (e.x >= tau) + (e.y >= tau) + (e.z >= tau) + (e.w >= tau);
    int off = 0;
    if (c) off = atomicAdd(&cnt_s, c);
    if (e.x >= tau) buf[off++] = e.x;
    if (e.y >= tau) buf[off++] = e.y;
    if (e.z >= tau) buf[off++] = e.z;
    if (e.w >= tau) buf[off++] = e.w;
    __syncthreads();
    int cnt = cnt_s;                         // cnt >= 48 guaranteed

    if (cnt <= 128) {
        if (wave == 0) {
            float a  = sort64_desc(buf[lane], lane);
            float b2 = sort64_desc(buf[64 + lane], lane);
            float br = __shfl(b2, 63 - lane);
            float hi = fmaxf(a, br);
            #pragma unroll
            for (int j = 32; j > 0; j >>= 1) {
                float o = __shfl_xor(hi, j);
                hi = ((lane & j) == 0) ? fmaxf(hi, o) : fminf(hi, o);
            }
            if (lane < T_) topv[(size_t)row * T_ + lane] = fmaxf(hi, 0.f);
        }
    } else {
        int P = 256; while (P < cnt) P <<= 1;     // pathological (ties) path
        for (int k = 2; k <= P; k <<= 1)
            for (int j = k >> 1; j > 0; j >>= 1) {
                for (int t2 = tid; t2 < P; t2 += 256) {
                    int ixj = t2 ^ j;
                    if (ixj > t2) {
                        float a = buf[t2], b3 = buf[ixj];
                        bool desc = ((t2 & k) == 0);
                        if (desc ? (a < b3) : (a > b3)) { buf[t2] = b3; buf[ixj] = a; }
                    }
                }
                __syncthreads();
            }
        if (tid < T_) topv[(size_t)row * T_ + tid] = fmaxf(buf[tid], 0.f);
    }
}

// ---------------------------------------------------------------------------
// 9) column norm over (B,H) and final transpose
// ---------------------------------------------------------------------------
__global__ void k_colss(const float* __restrict__ topv, float* __restrict__ colss) {
    int o = blockIdx.x;
    int w = o / T_, t = o % T_;
    int lane = threadIdx.x;
    float s = 0.f;
    for (int i = lane; i < 512; i += 64) {
        int b = i >> 5, h = i & 31;
        float v = topv[(size_t)((b << 10) + (h << 5) + w) * T_ + t];
        s += v * v;
    }
    for (int off = 32; off > 0; off >>= 1) s += __shfl_down(s, off);
    if (lane == 0) colss[o] = s;
}

__global__ void k_final(const float* __restrict__ topv, const float* __restrict__ colss,
                        float* __restrict__ out) {
    int idx = blockIdx.x * 256 + threadIdx.x;
    if (idx >= B_ * T_ * HW_) return;
    int w = idx & 31;
    int h = (idx >> 5) & 31;
    int t = (idx >> 10) % T_;
    int b = idx / (T_ * HW_);
    float v = topv[(size_t)((b << 10) + (h << 5) + w) * T_ + t];
    out[idx] = v * rsqrtf(colss[w * T_ + t]);
}

// ---------------------------------------------------------------------------
extern "C" void kernel_launch(void* const* d_in, const int* in_sizes, int n_in,
                              void* d_out, int out_size, void* d_ws, size_t ws_size,
                              hipStream_t stream) {
    const float* x     = (const float*)d_in[0];
    const float* fW    = (const float*)d_in[1];
    const float* fb    = (const float*)d_in[2];
    const float* gW    = (const float*)d_in[3];
    const float* gb    = (const float*)d_in[4];
    const float* hW    = (const float*)d_in[5];
    const float* hb    = (const float*)d_in[6];
    const float* scale = (const float*)d_in[7];
    float* out = (float*)d_out;

    // byte-offset workspace layout (~137.4 MB)
    char* wsb = (char*)d_ws;
    float* part = (float*)(wsb + 0);                 // 131072 B
    float* ninv = (float*)(wsb + 131072);            // 4096 B
    u16*   hWh  = (u16*)(wsb + 135168);              // 524288 B
    u16*   hWl  = (u16*)(wsb + 659456);              // 524288 B
    u16*   fgWh = (u16*)(wsb + 1183744);             // 131072 B
    u16*   fgWl = (u16*)(wsb + 1314816);             // 131072 B
    float* fgb  = (float*)(wsb + 1445888);           // 512 B
    u16*   xnH  = (u16*)(wsb + 1446400);             // 16777216 B (xn -> fdd)
    u16*   xnL  = (u16*)(wsb + 18223616);            // 16777216 B
    u16*   fgH  = (u16*)(wsb + 35000832);            // 4194304 B (later topv)
    u16*   fgL  = (u16*)(wsb + 39195136);            // 4194304 B (later colss)
    u16*   hvTH = (u16*)(wsb + 43389440);            // 16777216 B (later fddT)
    u16*   hvTL = (u16*)(wsb + 60166656);            // 16777216 B
    float* S    = (float*)(wsb + 76943872);          // 67108864 B (S -> P -> corr)
    float* topv = (float*)fgH;
    float* colss= (float*)fgL;

    const long sXn = 524288;    // elements per batch, [1024][512]
    const long sFG = 131072;    // [1024][128]
    const long sS  = 1048576;   // [1024][1024]

    // 1) per-pixel Frobenius norm
    k_colsq<<<128, 256, 0, stream>>>(x, part);
    k_rsqrt<<<4, 256, 0, stream>>>(part, ninv);

    // 2) normalized channel-last bf16-split planes
    k_transpose<<<dim3(32, 16, 16), dim3(32, 8), 0, stream>>>(x, ninv, xnH, xnL);

    // 3) weight planes
    k_packW<<<1024, 256, 0, stream>>>(hW, hWh, hWl);
    k_packFG<<<256, 256, 0, stream>>>(fW, gW, fb, gb, fgWh, fgWl, fgb);

    // 4) fg = xn @ [fW|gW]^T + [fb|gb]  (planar out [B,1024,128])
    k_mfmaP<0, 3><<<dim3(1, 8, 16), 256, 0, stream>>>(
        xnH, xnL, fgWh, fgWl, fgb, nullptr, fgH, fgL,
        128, 512, 512, 512, sXn, 0, sFG);

    // 5) hvT = hW @ xn^T + hb[row]  (planar out [B,512,1024])
    k_mfmaP<0, 1><<<dim3(8, 4, 16), 256, 0, stream>>>(
        hWh, hWl, xnH, xnL, hb, nullptr, hvTH, hvTL,
        1024, 512, 512, 512, 0, sXn, sXn);

    // 6) S = f @ perm(g)^T  (K=64, W-major keys), fp32
    k_mfmaP<1, 0><<<dim3(8, 8, 16), 256, 0, stream>>>(
        fgH, fgL, fgH + 64, fgL + 64, nullptr, S, nullptr, nullptr,
        1024, 64, 128, 128, sFG, sFG, sS);

    // 7) softmax rows -> P packed in place
    k_softmax<<<B_ * HW_, 256, 0, stream>>>(S);

    // 8) fdd = scale*(P @ hvT^T) + xn, planar in place over xn planes
    k_mfmaPV<<<dim3(4, 8, 16), 256, 0, stream>>>(
        (const unsigned*)S, hvTH, hvTL, xnH, xnL, scale,
        512, 1024, 1024, 1024, sS, sXn, sXn);

    // 9) fddT planes: transpose [512][1024] flat view into hvT buffers
    k_tposeU<<<dim3(32, 16, 32), dim3(32, 8), 0, stream>>>(xnH, xnL, hvTH, hvTL);

    // 10) corr = fdd @ fddT^T -> fp32 into S
    k_mfmaP<0, 0><<<dim3(8, 8, 16), 256, 0, stream>>>(
        xnH, xnL, hvTH, hvTL, nullptr, S, nullptr, nullptr,
        1024, 512, 512, 512, sXn, sXn, sS);

    // 11) top-48 desc + relu
    k_topk<<<B_ * HW_, 256, 0, stream>>>(S, topv);

    // 12) norm over (B,H) + output transpose
    k_colss<<<W_ * T_, 64, 0, stream>>>(topv, colss);
    k_final<<<(B_ * T_ * HW_ + 255) / 256, 256, 0, stream>>>(topv, colss, out);
}

// Round 4
// 287.384 us; speedup vs baseline: 3.5330x; 1.2134x over previous
//
#include <hip/hip_runtime.h>
#include <cstdint>
#include <cstddef>

#define B_   16
#define C_   512
#define H_   32
#define W_   32
#define HW_  1024
#define TC_  64
#define T_   48

typedef unsigned short u16;
typedef __attribute__((ext_vector_type(8))) short short8v;
typedef __attribute__((ext_vector_type(4))) float f32x4;

// ---------------------------------------------------------------------------
// bf16 helpers
// ---------------------------------------------------------------------------
__device__ __forceinline__ u16 tobf(float x) {
    unsigned u = __float_as_uint(x);
    return (u16)((u + 0x7FFFu + ((u >> 16) & 1u)) >> 16);    // RTNE
}
__device__ __forceinline__ unsigned pack_hilo(float x) {
    unsigned u = __float_as_uint(x);
    unsigned hi = (u + 0x7FFFu + ((u >> 16) & 1u)) >> 16;
    float hif = __uint_as_float(hi << 16);
    float lof = x - hif;
    unsigned ul = __float_as_uint(lof);
    unsigned lo = (ul + 0x7FFFu + ((ul >> 16) & 1u)) >> 16;
    return (hi << 16) | lo;
}
__device__ __forceinline__ float compose_hilo(u16 hi, u16 lo) {
    return __uint_as_float(((unsigned)hi) << 16) + __uint_as_float(((unsigned)lo) << 16);
}
__device__ __forceinline__ float frombf(u16 h) {
    return __uint_as_float(((unsigned)h) << 16);
}

__device__ __forceinline__ void gld16(const void* g, void* l) {
    __builtin_amdgcn_global_load_lds(
        (const __attribute__((address_space(1))) void*)g,
        (__attribute__((address_space(3))) void*)l, 16, 0, 0);
}

// ---------------------------------------------------------------------------
// 1) Frobenius-norm helpers
// ---------------------------------------------------------------------------
__global__ void k_colsq(const float* __restrict__ x, float* __restrict__ partial) {
    int bid = blockIdx.x;
    int col = (bid & 3) * 256 + threadIdx.x;
    int r0  = (bid >> 2) * 256;
    const float* p = x + (size_t)r0 * HW_ + col;
    float s = 0.f;
    for (int r = 0; r < 256; ++r) { float v = p[(size_t)r * HW_]; s += v * v; }
    partial[(size_t)(bid >> 2) * HW_ + col] = s;
}

__global__ void k_rsqrt(const float* __restrict__ partial, float* __restrict__ ninv) {
    int i = blockIdx.x * 256 + threadIdx.x;
    if (i < HW_) {
        float s = 0.f;
        for (int r = 0; r < 32; ++r) s += partial[(size_t)r * HW_ + i];
        ninv[i] = rsqrtf(s);
    }
}

// ---------------------------------------------------------------------------
// 2) transpose + normalize + split: x [B,C,HW] -> xn planes [B,HW,C] bf16 hi/lo
// ---------------------------------------------------------------------------
__global__ void k_transpose(const float* __restrict__ x, const float* __restrict__ ninv,
                            u16* __restrict__ obH, u16* __restrict__ obL) {
    __shared__ float tile[32][33];
    int b  = blockIdx.z;
    int m0 = blockIdx.x * 32, c0 = blockIdx.y * 32;
    int tx = threadIdx.x, ty = threadIdx.y;
    const float* xb = x + (size_t)b * C_ * HW_;
    #pragma unroll
    for (int j = 0; j < 32; j += 8)
        tile[ty + j][tx] = xb[(size_t)(c0 + ty + j) * HW_ + m0 + tx];
    __syncthreads();
    size_t base = (size_t)b * HW_ * C_;
    #pragma unroll
    for (int j = 0; j < 32; j += 8) {
        int m = m0 + ty + j;
        unsigned pk = pack_hilo(tile[tx][ty + j] * ninv[m]);
        size_t idx = base + (size_t)m * C_ + c0 + tx;
        obH[idx] = (u16)(pk >> 16);
        obL[idx] = (u16)pk;
    }
}

// ---------------------------------------------------------------------------
// 3) weight prep
// ---------------------------------------------------------------------------
__global__ void k_packW(const float* __restrict__ in, u16* __restrict__ oh,
                        u16* __restrict__ ol) {
    size_t i = (size_t)blockIdx.x * 256 + threadIdx.x;
    unsigned pk = pack_hilo(in[i]);
    oh[i] = (u16)(pk >> 16); ol[i] = (u16)pk;
}
__global__ void k_packFG(const float* __restrict__ fW, const float* __restrict__ gW,
                         const float* __restrict__ fb, const float* __restrict__ gb,
                         u16* __restrict__ oh, u16* __restrict__ ol,
                         float* __restrict__ fgb) {
    int idx = blockIdx.x * 256 + threadIdx.x;   // 65536
    int row = idx >> 9, c = idx & 511;
    float v = (row < 64) ? fW[row * 512 + c] : gW[(row - 64) * 512 + c];
    unsigned pk = pack_hilo(v);
    oh[idx] = (u16)(pk >> 16); ol[idx] = (u16)pk;
    if (idx < 128) fgb[idx] = (idx < 64) ? fb[idx] : gb[idx - 64];
}

// ---------------------------------------------------------------------------
// 4) unified planar bf16 MFMA GEMM: C = A[M,K] * B[N,K]^T
//    128x128 tile, BK=32, 4 waves. Planes: A hi [+A lo], B hi [+B lo].
//    Split terms: hh [+h*bl if SPLITB] [+al*bh if SPLITA].
//    LDS swizzle (verified r3): chunk li: rp=li*8+(lane>>3), gg=(lane&7)^(rp&7),
//    r=rp*2+(gg>>2), kc=k0+(gg&3)*8; fragment: rp=r>>1, gg=((r&1)<<2)+g,
//    off=rp*64+((gg^(rp&7))<<3).
//    EPI 0: Cf fp32 = acc
//    EPI 1: planar hi/lo = acc + bias[row]
//    EPI 2: Ch = bf16(scale*acc + compose(Ch,Cl))   (in-place fdd)
//    EPI 3: planar hi/lo = acc + bias[col]
//    EPI 4: Ch = bf16(acc)
// ---------------------------------------------------------------------------
template<int PERMB, int SPLITA, int SPLITB, int EPI>
__global__ __launch_bounds__(256) void k_gemm(
    const u16* __restrict__ Ah, const u16* __restrict__ Al,
    const u16* __restrict__ Bh, const u16* __restrict__ Bl,
    const float* __restrict__ bias,
    float* __restrict__ Cf, u16* __restrict__ Ch, u16* __restrict__ Cl,
    const float* __restrict__ scaleP,
    int N, int K, int lda, int ldb, long sA, long sB, long sC)
{
    constexpr int PLANES = 2 + SPLITA + SPLITB;
    constexpr int CPW = 2 * PLANES;             // staging chunks per wave
    __shared__ u16 lds[PLANES * 4096];

    const int b = blockIdx.z;
    const u16* pAh = Ah + (size_t)b * sA;
    const u16* pAl = SPLITA ? Al + (size_t)b * sA : nullptr;
    const u16* pBh = Bh + (size_t)b * sB;
    const u16* pBl = SPLITB ? Bl + (size_t)b * sB : nullptr;
    const int m0 = blockIdx.y * 128, n0 = blockIdx.x * 128;
    const int tid = threadIdx.x, wave = tid >> 6, lane = tid & 63;
    const int wm = wave >> 1, wn = wave & 1;
    const int g = lane >> 4;

    f32x4 acc[4][4];
    #pragma unroll
    for (int i = 0; i < 4; ++i)
        #pragma unroll
        for (int j = 0; j < 4; ++j) { f32x4 z = {0.f,0.f,0.f,0.f}; acc[i][j] = z; }

    for (int kt = 0; kt < (K >> 5); ++kt) {
        const int k0 = kt << 5;
        __syncthreads();
        #pragma unroll
        for (int q = 0; q < CPW; ++q) {
            int ci = wave * CPW + q;
            int pl = ci >> 3, li = ci & 7;
            bool isA = pl < (1 + SPLITA);
            const u16* gp;
            int lbase;
            if (pl == 0)                      { gp = pAh; lbase = 0; }
            else if (SPLITA && pl == 1)       { gp = pAl; lbase = 4096; }
            else if (pl == 1 + SPLITA)        { gp = pBh; lbase = (1 + SPLITA) * 4096; }
            else                              { gp = pBl; lbase = (2 + SPLITA) * 4096; }
            int ld = isA ? lda : ldb;
            int rb = isA ? m0 : n0;
            int rp = li * 8 + (lane >> 3);
            int gg = (lane & 7) ^ (rp & 7);
            int r  = rp * 2 + (gg >> 2);
            int kc = k0 + (gg & 3) * 8;
            int rowg = rb + r;
            if (PERMB && !isA) rowg = ((rowg & 31) << 5) | (rowg >> 5);
            gld16(gp + (size_t)rowg * ld + kc, lds + lbase + li * 512 + lane * 8);
        }
        __syncthreads();

        const u16* AsH = lds;
        const u16* AsL = lds + 4096;
        const u16* BsH = lds + (1 + SPLITA) * 4096;
        const u16* BsL = lds + (2 + SPLITA) * 4096;

        short8v ah[4], alv[4];
        #pragma unroll
        for (int i = 0; i < 4; ++i) {
            int r = wm * 64 + i * 16 + (lane & 15);
            int rp = r >> 1, gg = ((r & 1) << 2) + g;
            int off = rp * 64 + ((gg ^ (rp & 7)) << 3);
            ah[i] = *(const short8v*)(AsH + off);
            if (SPLITA) alv[i] = *(const short8v*)(AsL + off);
        }
        #pragma unroll
        for (int j = 0; j < 4; ++j) {
            int r = wn * 64 + j * 16 + (lane & 15);
            int rp = r >> 1, gg = ((r & 1) << 2) + g;
            int off = rp * 64 + ((gg ^ (rp & 7)) << 3);
            short8v bh = *(const short8v*)(BsH + off);
            short8v bl;
            if (SPLITB) bl = *(const short8v*)(BsL + off);
            #pragma unroll
            for (int i = 0; i < 4; ++i) {
                acc[i][j] = __builtin_amdgcn_mfma_f32_16x16x32_bf16(ah[i], bh, acc[i][j], 0, 0, 0);
                if (SPLITB)
                    acc[i][j] = __builtin_amdgcn_mfma_f32_16x16x32_bf16(ah[i], bl, acc[i][j], 0, 0, 0);
                if (SPLITA)
                    acc[i][j] = __builtin_amdgcn_mfma_f32_16x16x32_bf16(alv[i], bh, acc[i][j], 0, 0, 0);
            }
        }
    }

    const float sc = (EPI == 2) ? scaleP[0] : 0.f;
    const int colbase = n0 + wn * 64 + (lane & 15);
    const int rowbase = m0 + wm * 64 + ((lane >> 4) << 2);
    #pragma unroll
    for (int i = 0; i < 4; ++i)
        #pragma unroll
        for (int j = 0; j < 4; ++j) {
            int col = colbase + j * 16;
            #pragma unroll
            for (int rg = 0; rg < 4; ++rg) {
                int row = rowbase + i * 16 + rg;
                size_t idx = (size_t)b * sC + (size_t)row * N + col;
                float a = acc[i][j][rg];
                if (EPI == 0) {
                    Cf[idx] = a;
                } else if (EPI == 1 || EPI == 3) {
                    float v = a + ((EPI == 1) ? bias[row] : bias[col]);
                    unsigned pk = pack_hilo(v);
                    Ch[idx] = (u16)(pk >> 16); Cl[idx] = (u16)pk;
                } else if (EPI == 2) {
                    float v = sc * a + compose_hilo(Ch[idx], Cl[idx]);
                    Ch[idx] = tobf(v);
                } else {   // EPI == 4
                    Ch[idx] = tobf(a);
                }
            }
        }
}

// ---------------------------------------------------------------------------
// 5) row softmax on bf16 S, u16 in-place (row-exclusive, no cross-row race)
// ---------------------------------------------------------------------------
__global__ __launch_bounds__(256) void k_softmax(u16* __restrict__ S) {
    size_t row = blockIdx.x;
    u16* r = S + row * (size_t)HW_;
    int t = threadIdx.x;
    ushort4 raw = ((const ushort4*)r)[t];
    float v0 = frombf(raw.x), v1 = frombf(raw.y), v2 = frombf(raw.z), v3 = frombf(raw.w);

    __shared__ float redm[4], reds[4];
    int wid = t >> 6, lane = t & 63;

    float m = fmaxf(fmaxf(v0, v1), fmaxf(v2, v3));
    for (int o = 32; o > 0; o >>= 1) m = fmaxf(m, __shfl_down(m, o));
    if (lane == 0) redm[wid] = m;
    __syncthreads();
    if (t == 0) redm[0] = fmaxf(fmaxf(redm[0], redm[1]), fmaxf(redm[2], redm[3]));
    __syncthreads();
    m = redm[0];

    v0 = expf(v0 - m); v1 = expf(v1 - m); v2 = expf(v2 - m); v3 = expf(v3 - m);
    float s = v0 + v1 + v2 + v3;
    for (int o = 32; o > 0; o >>= 1) s += __shfl_down(s, o);
    if (lane == 0) reds[wid] = s;
    __syncthreads();
    if (t == 0) reds[0] = reds[0] + reds[1] + reds[2] + reds[3];
    __syncthreads();
    float inv = 1.f / reds[0];
    ushort4 o4;
    o4.x = tobf(v0 * inv); o4.y = tobf(v1 * inv);
    o4.z = tobf(v2 * inv); o4.w = tobf(v3 * inv);
    ((ushort4*)r)[t] = o4;
}

// ---------------------------------------------------------------------------
// 6) single-plane u16 transpose of fdd flat view [512][1024] -> fddT [1024][512]
// ---------------------------------------------------------------------------
__global__ void k_tposeU1(const u16* __restrict__ src, u16* __restrict__ dst) {
    __shared__ u16 tile[32][33];
    int b = blockIdx.z;
    const u16* sb = src + (size_t)b * (C_ * HW_);
    u16* db = dst + (size_t)b * (C_ * HW_);
    int c0 = blockIdx.x * 32, r0 = blockIdx.y * 32;     // src [512 r][1024 c]
    int tx = threadIdx.x, ty = threadIdx.y;
    #pragma unroll
    for (int j = 0; j < 32; j += 8)
        tile[ty + j][tx] = sb[(size_t)(r0 + ty + j) * HW_ + c0 + tx];
    __syncthreads();
    #pragma unroll
    for (int j = 0; j < 32; j += 8)
        db[(size_t)(c0 + ty + j) * C_ + r0 + tx] = tile[tx][ty + j];
}

// ---------------------------------------------------------------------------
// 7) top-48: tau-prune + compact + sort (verified r3)
// ---------------------------------------------------------------------------
__device__ __forceinline__ float sort64_desc(float v, int lane) {
    #pragma unroll
    for (int k = 2; k <= 64; k <<= 1) {
        #pragma unroll
        for (int j = k >> 1; j > 0; j >>= 1) {
            float o = __shfl_xor(v, j);
            bool takeMax = (((lane & k) == 0) == ((lane & j) == 0));
            v = takeMax ? fmaxf(v, o) : fminf(v, o);
        }
    }
    return v;
}
__device__ __forceinline__ float bmerge64_desc(float a, float b, int lane) {
    float br = __shfl(b, 63 - lane);
    float c = fmaxf(a, br);
    #pragma unroll
    for (int j = 32; j > 0; j >>= 1) {
        float o = __shfl_xor(c, j);
        c = ((lane & j) == 0) ? fmaxf(c, o) : fminf(c, o);
    }
    return c;
}

__global__ __launch_bounds__(256) void k_topk(const float* __restrict__ corr,
                                              float* __restrict__ topv) {
    int row = blockIdx.x, tid = threadIdx.x, wave = tid >> 6, lane = tid & 63;
    const float4 e = ((const float4*)(corr + (size_t)row * HW_))[tid];
    float gm = fmaxf(fmaxf(e.x, e.y), fmaxf(e.z, e.w));
    float v = sort64_desc(gm, lane);

    __shared__ float ls[4][64];
    __shared__ float tau_s;
    __shared__ int cnt_s;
    __shared__ float buf[1024];
    ls[wave][lane] = v;
    buf[tid] = -INFINITY; buf[tid + 256] = -INFINITY;
    buf[tid + 512] = -INFINITY; buf[tid + 768] = -INFINITY;
    if (tid == 0) cnt_s = 0;
    __syncthreads();

    if (wave == 0) {
        float ab = bmerge64_desc(ls[0][lane], ls[1][lane], lane);
        float cd = bmerge64_desc(ls[2][lane], ls[3][lane], lane);
        float t  = bmerge64_desc(ab, cd, lane);
        if (lane == T_ - 1) tau_s = t;
    }
    __syncthreads();
    float tau = tau_s;

    int c = (e.x >= tau) + (e.y >= tau) + (e.z >= tau) + (e.w >= tau);
    int off = 0;
    if (c) off = atomicAdd(&cnt_s, c);
    if (e.x >= tau) buf[off++] = e.x;
    if (e.y >= tau) buf[off++] = e.y;
    if (e.z >= tau) buf[off++] = e.z;
    if (e.w >= tau) buf[off++] = e.w;
    __syncthreads();
    int cnt = cnt_s;

    if (cnt <= 128) {
        if (wave == 0) {
            float a  = sort64_desc(buf[lane], lane);
            float b2 = sort64_desc(buf[64 + lane], lane);
            float br = __shfl(b2, 63 - lane);
            float hi = fmaxf(a, br);
            #pragma unroll
            for (int j = 32; j > 0; j >>= 1) {
                float o = __shfl_xor(hi, j);
                hi = ((lane & j) == 0) ? fmaxf(hi, o) : fminf(hi, o);
            }
            if (lane < T_) topv[(size_t)row * T_ + lane] = fmaxf(hi, 0.f);
        }
    } else {
        int P = 256; while (P < cnt) P <<= 1;
        for (int k = 2; k <= P; k <<= 1)
            for (int j = k >> 1; j > 0; j >>= 1) {
                for (int t2 = tid; t2 < P; t2 += 256) {
                    int ixj = t2 ^ j;
                    if (ixj > t2) {
                        float a = buf[t2], b3 = buf[ixj];
                        bool desc = ((t2 & k) == 0);
                        if (desc ? (a < b3) : (a > b3)) { buf[t2] = b3; buf[ixj] = a; }
                    }
                }
                __syncthreads();
            }
        if (tid < T_) topv[(size_t)row * T_ + tid] = fmaxf(buf[tid], 0.f);
    }
}

// ---------------------------------------------------------------------------
// 8) column norm over (B,H) and final transpose
// ---------------------------------------------------------------------------
__global__ void k_colss(const float* __restrict__ topv, float* __restrict__ colss) {
    int o = blockIdx.x;
    int w = o / T_, t = o % T_;
    int lane = threadIdx.x;
    float s = 0.f;
    for (int i = lane; i < 512; i += 64) {
        int b = i >> 5, h = i & 31;
        float v = topv[(size_t)((b << 10) + (h << 5) + w) * T_ + t];
        s += v * v;
    }
    for (int off = 32; off > 0; off >>= 1) s += __shfl_down(s, off);
    if (lane == 0) colss[o] = s;
}

__global__ void k_final(const float* __restrict__ topv, const float* __restrict__ colss,
                        float* __restrict__ out) {
    int idx = blockIdx.x * 256 + threadIdx.x;
    if (idx >= B_ * T_ * HW_) return;
    int w = idx & 31;
    int h = (idx >> 5) & 31;
    int t = (idx >> 10) % T_;
    int b = idx / (T_ * HW_);
    float v = topv[(size_t)((b << 10) + (h << 5) + w) * T_ + t];
    out[idx] = v * rsqrtf(colss[w * T_ + t]);
}

// ---------------------------------------------------------------------------
extern "C" void kernel_launch(void* const* d_in, const int* in_sizes, int n_in,
                              void* d_out, int out_size, void* d_ws, size_t ws_size,
                              hipStream_t stream) {
    const float* x     = (const float*)d_in[0];
    const float* fW    = (const float*)d_in[1];
    const float* fb    = (const float*)d_in[2];
    const float* gW    = (const float*)d_in[3];
    const float* gb    = (const float*)d_in[4];
    const float* hW    = (const float*)d_in[5];
    const float* hb    = (const float*)d_in[6];
    const float* scale = (const float*)d_in[7];
    float* out = (float*)d_out;

    // byte-offset workspace layout (~144 MB, proven available in r3)
    char* wsb = (char*)d_ws;
    float* part = (float*)(wsb + 0);                 // 131072 B
    float* ninv = (float*)(wsb + 131072);            // 4096 B
    u16*   hWh  = (u16*)(wsb + 135168);              // 524288 B
    u16*   hWl  = (u16*)(wsb + 659456);              // 524288 B
    u16*   fgWh = (u16*)(wsb + 1183744);             // 131072 B
    u16*   fgWl = (u16*)(wsb + 1314816);             // 131072 B
    float* fgb  = (float*)(wsb + 1445888);           // 512 B
    u16*   xnH  = (u16*)(wsb + 1446400);             // 16777216 B (xn hi -> fdd bf16)
    u16*   xnL  = (u16*)(wsb + 18223616);            // 16777216 B (xn lo)
    u16*   fgH  = (u16*)(wsb + 35000832);            // 4194304 B (later topv)
    u16*   fgL  = (u16*)(wsb + 39195136);            // 4194304 B (later colss)
    u16*   hvTH = (u16*)(wsb + 43389440);            // 16777216 B (later fddT)
    u16*   hvTL = (u16*)(wsb + 60166656);            // 16777216 B
    float* S    = (float*)(wsb + 76943872);          // 67108864 B (S/P u16 -> corr fp32)
    float* topv = (float*)fgH;
    float* colss= (float*)fgL;
    u16*   Sp   = (u16*)S;                           // u16 S/P view [B*1024][1024]

    const long sXn = 524288;    // [1024][512] elements per batch
    const long sFG = 131072;    // [1024][128]
    const long sS  = 1048576;   // [1024][1024]

    // 1) per-pixel Frobenius norm
    k_colsq<<<128, 256, 0, stream>>>(x, part);
    k_rsqrt<<<4, 256, 0, stream>>>(part, ninv);

    // 2) normalized channel-last bf16-split planes
    k_transpose<<<dim3(32, 16, 16), dim3(32, 8), 0, stream>>>(x, ninv, xnH, xnL);

    // 3) weight planes
    k_packW<<<1024, 256, 0, stream>>>(hW, hWh, hWl);
    k_packFG<<<256, 256, 0, stream>>>(fW, gW, fb, gb, fgWh, fgWl, fgb);

    // 4) fg = xn @ [fW|gW]^T + bias[col]  (3-term, planar out [B,1024,128])
    k_gemm<0, 1, 1, 3><<<dim3(1, 8, 16), 256, 0, stream>>>(
        xnH, xnL, fgWh, fgWl, fgb, nullptr, fgH, fgL, nullptr,
        128, 512, 512, 512, sXn, 0, sFG);

    // 5) hvT = hW @ xn^T + hb[row]  (3-term, planar out [B,512,1024])
    k_gemm<0, 1, 1, 1><<<dim3(8, 4, 16), 256, 0, stream>>>(
        hWh, hWl, xnH, xnL, hb, nullptr, hvTH, hvTL, nullptr,
        1024, 512, 512, 512, 0, sXn, sXn);

    // 6) S = f @ perm(g)^T  (3-term, K=64, W-major keys) -> bf16 u16
    k_gemm<1, 1, 1, 4><<<dim3(8, 8, 16), 256, 0, stream>>>(
        fgH, fgL, fgH + 64, fgL + 64, nullptr, nullptr, Sp, nullptr, nullptr,
        1024, 64, 128, 128, sFG, sFG, sS);

    // 7) softmax rows, u16 in place -> P bf16
    k_softmax<<<B_ * HW_, 256, 0, stream>>>(Sp);

    // 8) fdd = bf16(scale*(P @ hvT^T) + xn), single plane in place over xnH
    k_gemm<0, 0, 1, 2><<<dim3(4, 8, 16), 256, 0, stream>>>(
        Sp, nullptr, hvTH, hvTL, nullptr, nullptr, xnH, xnL, scale,
        512, 1024, 1024, 1024, sS, sXn, sXn);

    // 9) fddT: transpose flat [512][1024] view of fddH -> hvTH [1024][512]
    k_tposeU1<<<dim3(32, 16, 16), dim3(32, 8), 0, stream>>>(xnH, hvTH);

    // 10) corr = fdd @ fddT^T (1-term bf16) -> fp32 into S
    k_gemm<0, 0, 0, 0><<<dim3(8, 8, 16), 256, 0, stream>>>(
        xnH, nullptr, hvTH, nullptr, nullptr, S, nullptr, nullptr, nullptr,
        1024, 512, 512, 512, sXn, sXn, sS);

    // 11) top-48 desc + relu
    k_topk<<<B_ * HW_, 256, 0, stream>>>(S, topv);

    // 12) norm over (B,H) + output transpose
    k_colss<<<W_ * T_, 64, 0, stream>>>(topv, colss);
    k_final<<<(B_ * T_ * HW_ + 255) / 256, 256, 0, stream>>>(topv, colss, out);
}